// Round 1
// baseline (277.702 us; speedup 1.0000x reference)
//
#include <hip/hip_runtime.h>
#include <math.h>

#define N_SYM 128
#define BATCH 131072
#define LEV   30.0f

// One thread per batch column. The scan over the 128 symbols is sequential
// (unused-margin carry), but the 4 input streams are carry-independent, so we
// prefetch the next symbol's values one iteration ahead and let unroll-4 batch
// the vmem issues. All global accesses are lane-stride-1 dwords (coalesced).
// Per-symbol constants (msm_min/step/max) are uniform-indexed -> s_load.
__global__ __launch_bounds__(256) void lle_scan_kernel(
    const float* __restrict__ frac,
    const float* __restrict__ exs,
    const float* __restrict__ pos,
    const float* __restrict__ mrate,
    const float* __restrict__ um0,
    const float* __restrict__ msm_min,
    const float* __restrict__ msm_step,
    const float* __restrict__ msm_max,
    float* __restrict__ out)
{
    const int col = blockIdx.x * blockDim.x + threadIdx.x;

    float um = um0[col];

    size_t idx = (size_t)col;
    // prefetch symbol 0
    float f = frac[idx];
    float e = exs[idx];
    float p = pos[idx];
    float m = mrate[idx];

#pragma unroll 4
    for (int s = 0; s < N_SYM; ++s) {
        const size_t nidx = idx + (size_t)BATCH;
        float fn = 0.0f, en = 0.0f, pn = 0.0f, mn2 = 0.0f;
        if (s + 1 < N_SYM) {              // uniform branch, no divergence
            fn  = frac[nidx];
            en  = exs[nidx];
            pn  = pos[nidx];
            mn2 = mrate[nidx];
        }

        const float mrl = m * LEV;                 // margin_rate * leverage
        const float us  = um * mrl;                // unused_size
        const float mps = fabsf(p) + us;           // max_pos_size
        const float adj = fminf((p * f > 0.0f) ? us : mps, 0.0f);
        const float nps = f * (mps - adj);         // new_pos_size (pre-round)

        float       a  = fabsf(nps);
        const float sg = copysignf(1.0f, nps);     // == sign() except at 0,
                                                   // where a==0 anyway

        const float stp = msm_step[s];
        a = floorf(a / stp) * stp;                 // quantize to step
        a = (a < msm_min[s]) ? 0.0f : a;           // below-min -> 0
        a = fminf(a, msm_max[s]);                  // clamp to max

        out[idx] = e * (sg * a) + (1.0f - e) * p;

        um = (mps - a) / mrl;                      // carry

        f = fn; e = en; p = pn; m = mn2;
        idx = nidx;
    }

    out[(size_t)N_SYM * (size_t)BATCH + (size_t)col] = um;
}

extern "C" void kernel_launch(void* const* d_in, const int* in_sizes, int n_in,
                              void* d_out, int out_size, void* d_ws, size_t ws_size,
                              hipStream_t stream) {
    const float* frac     = (const float*)d_in[0];
    const float* exs      = (const float*)d_in[1];
    const float* pos      = (const float*)d_in[2];
    const float* mrate    = (const float*)d_in[3];
    const float* um0      = (const float*)d_in[4];
    const float* msm_min  = (const float*)d_in[5];
    const float* msm_step = (const float*)d_in[6];
    const float* msm_max  = (const float*)d_in[7];
    float* out = (float*)d_out;

    const int block = 256;
    const int grid  = BATCH / block;   // 512 blocks -> 2 blocks/CU resident

    hipLaunchKernelGGL(lle_scan_kernel, dim3(grid), dim3(block), 0, stream,
                       frac, exs, pos, mrate, um0, msm_min, msm_step, msm_max,
                       out);
}

// Round 2
// 275.871 us; speedup vs baseline: 1.0066x; 1.0066x over previous
//
#include <hip/hip_runtime.h>
#include <math.h>

#define N_SYM 128
#define BATCH 131072
#define LEV   30.0f
#define PF    8   // prefetch depth: 4 streams x 8 deep = 32 pending dwords/lane

// One thread per batch column; sequential 128-symbol scan (unused-margin
// carry). Occupancy is grid-capped at 8 waves/CU (131072 lanes), so latency
// hiding must come from per-lane MLP: an explicit PF-deep prefetch ring keeps
// 32 loads in flight per lane (~17 MB chip-wide). Outer loop unrolled by PF
// (body ~2.4 KB, fits L1I); final PF iterations peeled so the hot loop is
// branch-free. Stores are nontemporal so the 66 MB of write-once output
// doesn't evict L3-warm inputs.
__global__ __launch_bounds__(256) void lle_scan_kernel(
    const float* __restrict__ frac,
    const float* __restrict__ exs,
    const float* __restrict__ pos,
    const float* __restrict__ mrate,
    const float* __restrict__ um0,
    const float* __restrict__ msm_min,
    const float* __restrict__ msm_step,
    const float* __restrict__ msm_max,
    float* __restrict__ out)
{
    const int col = blockIdx.x * blockDim.x + threadIdx.x;

    float um = um0[col];

    float fb[PF], eb[PF], pb[PF], mb[PF];

    // warm the ring: symbols 0..PF-1
#pragma unroll
    for (int j = 0; j < PF; ++j) {
        const size_t o = (size_t)j * BATCH + (size_t)col;
        fb[j] = frac[o];
        eb[j] = exs[o];
        pb[j] = pos[o];
        mb[j] = mrate[o];
    }

    // hot loop: symbols 0..N_SYM-PF-1, unconditional prefetch of s+PF
    for (int s0 = 0; s0 < N_SYM - PF; s0 += PF) {
#pragma unroll
        for (int j = 0; j < PF; ++j) {
            const int s = s0 + j;
            const float f = fb[j];
            const float e = eb[j];
            const float p = pb[j];
            const float m = mb[j];

            {   // refill ring slot j with symbol s+PF
                const size_t o = (size_t)(s + PF) * BATCH + (size_t)col;
                fb[j] = frac[o];
                eb[j] = exs[o];
                pb[j] = pos[o];
                mb[j] = mrate[o];
            }

            const float mrl = m * LEV;
            const float us  = um * mrl;                  // unused_size
            const float mps = fabsf(p) + us;             // max_pos_size
            const float adj = fminf((p * f > 0.0f) ? us : mps, 0.0f);
            const float nps = f * (mps - adj);

            float       a  = fabsf(nps);
            const float sg = copysignf(1.0f, nps);
            const float st = msm_step[s];
            a = floorf(a / st) * st;
            a = (a < msm_min[s]) ? 0.0f : a;
            a = fminf(a, msm_max[s]);

            const float res = e * (sg * a) + (1.0f - e) * p;
            __builtin_nontemporal_store(res, &out[(size_t)s * BATCH + (size_t)col]);

            um = (mps - a) / mrl;                        // carry
        }
    }

    // peeled tail: last PF symbols, no prefetch
#pragma unroll
    for (int j = 0; j < PF; ++j) {
        const int s = N_SYM - PF + j;
        const float f = fb[j];
        const float e = eb[j];
        const float p = pb[j];
        const float m = mb[j];

        const float mrl = m * LEV;
        const float us  = um * mrl;
        const float mps = fabsf(p) + us;
        const float adj = fminf((p * f > 0.0f) ? us : mps, 0.0f);
        const float nps = f * (mps - adj);

        float       a  = fabsf(nps);
        const float sg = copysignf(1.0f, nps);
        const float st = msm_step[s];
        a = floorf(a / st) * st;
        a = (a < msm_min[s]) ? 0.0f : a;
        a = fminf(a, msm_max[s]);

        const float res = e * (sg * a) + (1.0f - e) * p;
        __builtin_nontemporal_store(res, &out[(size_t)s * BATCH + (size_t)col]);

        um = (mps - a) / mrl;
    }

    __builtin_nontemporal_store(um, &out[(size_t)N_SYM * BATCH + (size_t)col]);
}

extern "C" void kernel_launch(void* const* d_in, const int* in_sizes, int n_in,
                              void* d_out, int out_size, void* d_ws, size_t ws_size,
                              hipStream_t stream) {
    const float* frac     = (const float*)d_in[0];
    const float* exs      = (const float*)d_in[1];
    const float* pos      = (const float*)d_in[2];
    const float* mrate    = (const float*)d_in[3];
    const float* um0      = (const float*)d_in[4];
    const float* msm_min  = (const float*)d_in[5];
    const float* msm_step = (const float*)d_in[6];
    const float* msm_max  = (const float*)d_in[7];
    float* out = (float*)d_out;

    const int block = 256;
    const int grid  = BATCH / block;   // 512 blocks

    hipLaunchKernelGGL(lle_scan_kernel, dim3(grid), dim3(block), 0, stream,
                       frac, exs, pos, mrate, um0, msm_min, msm_step, msm_max,
                       out);
}